// Round 2
// baseline (269.051 us; speedup 1.0000x reference)
//
#include <hip/hip_runtime.h>
#include <hip/hip_fp16.h>

#define BB 32
#define NN 512
#define DD 256
#define NEG_INF -9e15f

typedef _Float16 half8 __attribute__((ext_vector_type(8)));
typedef _Float16 half4 __attribute__((ext_vector_type(4)));
typedef float v4f __attribute__((ext_vector_type(4)));
typedef float f4v __attribute__((ext_vector_type(4)));

// ---------------- pre-kernel: fp32 -> fp16 convert + transpose (vectorized) ----------------
__global__ __launch_bounds__(256) void cvt_kernel(const float* __restrict__ h,
                                                  _Float16* __restrict__ h16,
                                                  _Float16* __restrict__ h16t) {
    __shared__ _Float16 tile[32][36];   // +4 pad keeps half4 rows 8B-aligned, ~2-way banks
    const int d0 = blockIdx.x * 32;
    const int n0 = blockIdx.y * 32;
    const int b  = blockIdx.z;
    const int t  = threadIdx.x;

    // read: thread covers 4 contiguous d of one n-row
    const int nl = t >> 3;          // 0..31
    const int dq = (t & 7) * 4;     // 0,4,...,28
    f4v v = *(const f4v*)(h + ((size_t)b * NN + (n0 + nl)) * DD + d0 + dq);
    half4 hv = { (_Float16)v.x, (_Float16)v.y, (_Float16)v.z, (_Float16)v.w };
    *(half4*)(h16 + ((size_t)b * NN + (n0 + nl)) * DD + d0 + dq) = hv;
    *(half4*)(&tile[nl][dq]) = hv;
    __syncthreads();

    // write transposed: thread covers 4 contiguous n of one d-row
    const int dl = t >> 3;          // 0..31
    const int nq = (t & 7) * 4;     // 0,4,...,28
    half4 o = { tile[nq][dl], tile[nq + 1][dl], tile[nq + 2][dl], tile[nq + 3][dl] };
    *(half4*)(h16t + ((size_t)b * DD + (d0 + dl)) * NN + n0 + nq) = o;
}

// ---------------- fused GAT kernel ----------------
// Grid: BB*(NN/16) = 1024 blocks of 256 threads. Block = (b, 16-row i-block).
// Phase 1/2: wave w handles j-quarter [w*128, w*128+128).
// Phase 3:   wave w handles d-quarter [w*64, w*64+64).
__global__ __launch_bounds__(256, 4) void gat_kernel(
    const _Float16* __restrict__ h16,   // [B][N][D]
    const _Float16* __restrict__ h16t,  // [B][D][N]
    const int* __restrict__ adj,        // [B][N][N]
    const float* __restrict__ a0, const float* __restrict__ a1,
    const float* __restrict__ a2, const float* __restrict__ a3,
    float* __restrict__ out)            // [B][N][D]
{
    __shared__ _Float16 sA[4][DD];            // 2 KB: the 4 attention vectors
    __shared__ _Float16 sAlpha[16][NN + 8];   // 16.6 KB: unnormalized alpha, fp16
    __shared__ float sRedM[4][16];            // per-wave row-max partials
    __shared__ float sRedS[4][16];            // per-wave row-sum partials

    const int tid  = threadIdx.x;
    const int wave = tid >> 6;
    const int lane = tid & 63;
    const int c    = lane & 15;   // MFMA: A.m / B.n / C.col
    const int q    = lane >> 4;   // MFMA: k-quad; C.row = q*4+reg

    const int blk  = blockIdx.x;
    const int b    = blk >> 5;    // NN/16 = 32 i-blocks per batch
    const int iblk = blk & 31;
    const int i0   = iblk * 16;

    // stage a_k as fp16 (tid == d, blockDim == DD)
    sA[0][tid] = (_Float16)a0[tid];
    sA[1][tid] = (_Float16)a1[tid];
    sA[2][tid] = (_Float16)a2[tid];
    sA[3][tid] = (_Float16)a3[tid];
    __syncthreads();

    const _Float16* Hb   = h16 + (size_t)b * NN * DD;
    const int*      adjb = adj + (size_t)b * NN * NN;

    // hoist the A-side h fragments (row i0+c, all 8 K-steps): 32 VGPRs
    half8 hfrag[8];
    {
        const _Float16* hrow = Hb + (size_t)(i0 + c) * DD;
#pragma unroll
        for (int s = 0; s < 8; ++s)
            hfrag[s] = *(const half8*)(hrow + s * 32 + q * 8);
    }

    const int jbase = wave * 128;
    v4f S[8];   // selected scores for this wave's 16 rows x 128 j

    // ---------------- phase 1: scores (4 e_k via MFMA) + select + leaky ----------------
#pragma unroll
    for (int g = 0; g < 2; ++g) {
        const int jg0 = jbase + g * 64;
        v4f e[4][4];
#pragma unroll
        for (int k = 0; k < 4; ++k)
#pragma unroll
            for (int jt = 0; jt < 4; ++jt)
                e[k][jt] = (v4f){0.f, 0.f, 0.f, 0.f};

#pragma unroll
        for (int s = 0; s < 8; ++s) {
            half8 bfrag[4];
#pragma unroll
            for (int jt = 0; jt < 4; ++jt)
                bfrag[jt] = *(const half8*)(Hb + (size_t)(jg0 + jt * 16 + c) * DD + s * 32 + q * 8);
            half8 aw[4];
#pragma unroll
            for (int k = 0; k < 4; ++k)
                aw[k] = *(const half8*)(&sA[k][s * 32 + q * 8]);
#pragma unroll
            for (int k = 0; k < 4; ++k) {
                half8 af = hfrag[s] * aw[k];   // (h_i * a_k) on the fly, v_pk_mul_f16
#pragma unroll
                for (int jt = 0; jt < 4; ++jt)
                    e[k][jt] = __builtin_amdgcn_mfma_f32_16x16x32_f16(af, bfrag[jt], e[k][jt], 0, 0, 0);
            }
        }
        // adj-based selection + leaky_relu (leaky commutes with the select)
#pragma unroll
        for (int jt = 0; jt < 4; ++jt) {
            const int j = jg0 + jt * 16 + c;
#pragma unroll
            for (int r = 0; r < 4; ++r) {
                const int i = i0 + q * 4 + r;
                const int v = adjb[(size_t)i * NN + j];
                float sc = (v == 1) ? e[0][jt][r]
                         : (v == 2) ? e[1][jt][r]
                         : (v == 3) ? e[2][jt][r]
                         : (v == 4) ? e[3][jt][r] : NEG_INF;
                sc = sc > 0.f ? sc : 0.2f * sc;
                S[g * 4 + jt][r] = sc;
            }
        }
    }

    // ---------------- phase 2: softmax over j (4-wave combine) ----------------
    float m4[4];
#pragma unroll
    for (int r = 0; r < 4; ++r) {
        float m = S[0][r];
#pragma unroll
        for (int t = 1; t < 8; ++t) m = fmaxf(m, S[t][r]);
#pragma unroll
        for (int off = 1; off < 16; off <<= 1)
            m = fmaxf(m, __shfl_xor(m, off, 64));
        m4[r] = m;
    }
    if (c == 0) {
#pragma unroll
        for (int r = 0; r < 4; ++r) sRedM[wave][q * 4 + r] = m4[r];
    }
    __syncthreads();

    float mf[4], sum4[4];
#pragma unroll
    for (int r = 0; r < 4; ++r) {
        float m = sRedM[0][q * 4 + r];
        m = fmaxf(m, sRedM[1][q * 4 + r]);
        m = fmaxf(m, sRedM[2][q * 4 + r]);
        m = fmaxf(m, sRedM[3][q * 4 + r]);
        mf[r]   = m;
        sum4[r] = 0.f;
    }
#pragma unroll
    for (int t = 0; t < 8; ++t) {
        const int j = jbase + t * 16 + c;
#pragma unroll
        for (int r = 0; r < 4; ++r) {
            float p = __expf(S[t][r] - mf[r]);   // NEG_INF path underflows to 0
            sum4[r] += p;
            sAlpha[q * 4 + r][j] = (_Float16)p;
        }
    }
#pragma unroll
    for (int r = 0; r < 4; ++r) {
#pragma unroll
        for (int off = 1; off < 16; off <<= 1)
            sum4[r] += __shfl_xor(sum4[r], off, 64);
    }
    if (c == 0) {
#pragma unroll
        for (int r = 0; r < 4; ++r) sRedS[wave][q * 4 + r] = sum4[r];
    }
    __syncthreads();   // covers sAlpha + sRedS writes

    // ---------------- phase 3: out = alpha @ H, wave = 64-d quarter ----------------
    const _Float16* Htb = h16t + (size_t)b * DD * NN;
    const int dq0 = wave * 64;
    v4f o[4];
#pragma unroll
    for (int nt = 0; nt < 4; ++nt) o[nt] = (v4f){0.f, 0.f, 0.f, 0.f};

#pragma unroll
    for (int ks = 0; ks < 16; ++ks) {
        const int j0 = ks * 32;
        half8 af = *(const half8*)(&sAlpha[c][j0 + q * 8]);
        half8 bf[4];
#pragma unroll
        for (int nt = 0; nt < 4; ++nt)
            bf[nt] = *(const half8*)(Htb + (size_t)(dq0 + nt * 16 + c) * NN + j0 + q * 8);
#pragma unroll
        for (int nt = 0; nt < 4; ++nt)
            o[nt] = __builtin_amdgcn_mfma_f32_16x16x32_f16(af, bf[nt], o[nt], 0, 0, 0);
    }

    float* outb = out + (size_t)b * NN * DD;
#pragma unroll
    for (int r = 0; r < 4; ++r) {
        const int irow = q * 4 + r;
        const float rinv = 1.f / (sRedS[0][irow] + sRedS[1][irow] +
                                  sRedS[2][irow] + sRedS[3][irow]);
#pragma unroll
        for (int nt = 0; nt < 4; ++nt) {
            const int d = dq0 + nt * 16 + c;
            outb[(size_t)(i0 + irow) * DD + d] = o[nt][r] * rinv;
        }
    }
}

// ---------------- launcher ----------------
extern "C" void kernel_launch(void* const* d_in, const int* in_sizes, int n_in,
                              void* d_out, int out_size, void* d_ws, size_t ws_size,
                              hipStream_t stream) {
    const float* hidden = (const float*)d_in[0];
    const int*   adjp   = (const int*)d_in[1];
    const float* a0     = (const float*)d_in[2];
    const float* a1     = (const float*)d_in[3];
    const float* a2     = (const float*)d_in[4];
    const float* a3     = (const float*)d_in[5];
    float* outp = (float*)d_out;

    _Float16* h16  = (_Float16*)d_ws;
    _Float16* h16t = h16 + (size_t)BB * NN * DD;

    dim3 g1(DD / 32, NN / 32, BB);
    cvt_kernel<<<g1, 256, 0, stream>>>(hidden, h16, h16t);

    gat_kernel<<<BB * (NN / 16), 256, 0, stream>>>(h16, h16t, adjp, a0, a1, a2, a3, outp);
}

// Round 3
// 181.412 us; speedup vs baseline: 1.4831x; 1.4831x over previous
//
#include <hip/hip_runtime.h>
#include <hip/hip_fp16.h>

#define BB 32
#define NN 512
#define DD 256
#define NEG_INF -9e15f

typedef _Float16 half8 __attribute__((ext_vector_type(8)));
typedef _Float16 half4 __attribute__((ext_vector_type(4)));
typedef float v4f __attribute__((ext_vector_type(4)));
typedef float f4v __attribute__((ext_vector_type(4)));

// ---------------- pre-kernel: fp32 -> fp16 convert + transpose (vectorized) ----------------
__global__ __launch_bounds__(256) void cvt_kernel(const float* __restrict__ h,
                                                  _Float16* __restrict__ h16,
                                                  _Float16* __restrict__ h16t) {
    __shared__ _Float16 tile[32][36];
    const int d0 = blockIdx.x * 32;
    const int n0 = blockIdx.y * 32;
    const int b  = blockIdx.z;
    const int t  = threadIdx.x;

    const int nl = t >> 3;          // 0..31
    const int dq = (t & 7) * 4;     // 0,4,...,28
    f4v v = *(const f4v*)(h + ((size_t)b * NN + (n0 + nl)) * DD + d0 + dq);
    half4 hv = { (_Float16)v.x, (_Float16)v.y, (_Float16)v.z, (_Float16)v.w };
    *(half4*)(h16 + ((size_t)b * NN + (n0 + nl)) * DD + d0 + dq) = hv;
    *(half4*)(&tile[nl][dq]) = hv;
    __syncthreads();

    const int dl = t >> 3;          // 0..31
    const int nq = (t & 7) * 4;     // 0,4,...,28
    half4 o = { tile[nq][dl], tile[nq + 1][dl], tile[nq + 2][dl], tile[nq + 3][dl] };
    *(half4*)(h16t + ((size_t)b * DD + (d0 + dl)) * NN + n0 + nq) = o;
}

// ---------------- fused GAT kernel ----------------
// Grid: BB*(NN/16) = 1024 blocks of 256 threads. Block = (b, 16-row i-block).
// Phase 1/2: wave w handles j-quarter [w*128, w*128+128) in 4 chunks of 32 j.
// Phase 3:   wave w handles d-quarter [w*64, w*64+64).
// Register budget: S[8]=32 + e[4][2]=32 + temps ~40 -> fits 128 @ 4 waves/EU, no spill.
__global__ __launch_bounds__(256, 4) void gat_kernel(
    const _Float16* __restrict__ h16,   // [B][N][D]
    const _Float16* __restrict__ h16t,  // [B][D][N]
    const int* __restrict__ adj,        // [B][N][N]
    const float* __restrict__ a0, const float* __restrict__ a1,
    const float* __restrict__ a2, const float* __restrict__ a3,
    float* __restrict__ out)            // [B][N][D]
{
    __shared__ _Float16 sA[4][DD];            // 2 KB
    __shared__ _Float16 sAlpha[16][NN + 8];   // 16.6 KB
    __shared__ float sRedM[4][16];
    __shared__ float sRedS[4][16];

    const int tid  = threadIdx.x;
    const int wave = tid >> 6;
    const int lane = tid & 63;
    const int c    = lane & 15;   // MFMA: A.m / B.n / C.col
    const int q    = lane >> 4;   // MFMA: k-quad; C.row = q*4+reg

    const int blk  = blockIdx.x;
    const int b    = blk >> 5;    // 32 i-blocks per batch
    const int iblk = blk & 31;
    const int i0   = iblk * 16;

    sA[0][tid] = (_Float16)a0[tid];
    sA[1][tid] = (_Float16)a1[tid];
    sA[2][tid] = (_Float16)a2[tid];
    sA[3][tid] = (_Float16)a3[tid];
    __syncthreads();

    const _Float16* Hb   = h16 + (size_t)b * NN * DD;
    const int*      adjb = adj + (size_t)b * NN * NN;
    const _Float16* hrow = Hb + (size_t)(i0 + c) * DD;   // this lane's A-side row

    const int jbase = wave * 128;
    v4f S[8];   // selected scores: 16 rows x 128 j per wave

    // ---------------- phase 1: scores + select + leaky, 4 chunks of 32 j ----------------
#pragma unroll
    for (int g = 0; g < 4; ++g) {
        const int jg0 = jbase + g * 32;
        v4f e[4][2];
#pragma unroll
        for (int k = 0; k < 4; ++k)
#pragma unroll
            for (int jt = 0; jt < 2; ++jt)
                e[k][jt] = (v4f){0.f, 0.f, 0.f, 0.f};

#pragma unroll
        for (int s = 0; s < 8; ++s) {
            half8 hf = *(const half8*)(hrow + s * 32 + q * 8);   // L1-hit after g=0
            half8 bfrag[2];
#pragma unroll
            for (int jt = 0; jt < 2; ++jt)
                bfrag[jt] = *(const half8*)(Hb + (size_t)(jg0 + jt * 16 + c) * DD + s * 32 + q * 8);
#pragma unroll
            for (int k = 0; k < 4; ++k) {
                half8 aw = *(const half8*)(&sA[k][s * 32 + q * 8]);
                half8 af = hf * aw;   // (h_i * a_k) on the fly
#pragma unroll
                for (int jt = 0; jt < 2; ++jt)
                    e[k][jt] = __builtin_amdgcn_mfma_f32_16x16x32_f16(af, bfrag[jt], e[k][jt], 0, 0, 0);
            }
        }
#pragma unroll
        for (int jt = 0; jt < 2; ++jt) {
            const int j = jg0 + jt * 16 + c;
#pragma unroll
            for (int r = 0; r < 4; ++r) {
                const int i = i0 + q * 4 + r;
                const int v = adjb[(size_t)i * NN + j];
                float sc = (v == 1) ? e[0][jt][r]
                         : (v == 2) ? e[1][jt][r]
                         : (v == 3) ? e[2][jt][r]
                         : (v == 4) ? e[3][jt][r] : NEG_INF;
                sc = sc > 0.f ? sc : 0.2f * sc;
                S[g * 2 + jt][r] = sc;
            }
        }
    }

    // ---------------- phase 2: softmax over j (4-wave combine) ----------------
    float m4[4];
#pragma unroll
    for (int r = 0; r < 4; ++r) {
        float m = S[0][r];
#pragma unroll
        for (int t = 1; t < 8; ++t) m = fmaxf(m, S[t][r]);
#pragma unroll
        for (int off = 1; off < 16; off <<= 1)
            m = fmaxf(m, __shfl_xor(m, off, 64));
        m4[r] = m;
    }
    if (c == 0) {
#pragma unroll
        for (int r = 0; r < 4; ++r) sRedM[wave][q * 4 + r] = m4[r];
    }
    __syncthreads();

    float mf[4], sum4[4];
#pragma unroll
    for (int r = 0; r < 4; ++r) {
        float m = sRedM[0][q * 4 + r];
        m = fmaxf(m, sRedM[1][q * 4 + r]);
        m = fmaxf(m, sRedM[2][q * 4 + r]);
        m = fmaxf(m, sRedM[3][q * 4 + r]);
        mf[r]   = m;
        sum4[r] = 0.f;
    }
#pragma unroll
    for (int t = 0; t < 8; ++t) {
        const int j = jbase + t * 16 + c;
#pragma unroll
        for (int r = 0; r < 4; ++r) {
            float p = __expf(S[t][r] - mf[r]);   // NEG_INF path underflows to 0
            sum4[r] += p;
            sAlpha[q * 4 + r][j] = (_Float16)p;
        }
    }
#pragma unroll
    for (int r = 0; r < 4; ++r) {
#pragma unroll
        for (int off = 1; off < 16; off <<= 1)
            sum4[r] += __shfl_xor(sum4[r], off, 64);
    }
    if (c == 0) {
#pragma unroll
        for (int r = 0; r < 4; ++r) sRedS[wave][q * 4 + r] = sum4[r];
    }
    __syncthreads();

    // ---------------- phase 3: out = alpha @ H, wave = 64-d quarter ----------------
    const _Float16* Htb = h16t + (size_t)b * DD * NN;
    const int dq0 = wave * 64;
    v4f o[4];
#pragma unroll
    for (int nt = 0; nt < 4; ++nt) o[nt] = (v4f){0.f, 0.f, 0.f, 0.f};

#pragma unroll
    for (int ks = 0; ks < 16; ++ks) {
        const int j0 = ks * 32;
        half8 af = *(const half8*)(&sAlpha[c][j0 + q * 8]);
        half8 bf[4];
#pragma unroll
        for (int nt = 0; nt < 4; ++nt)
            bf[nt] = *(const half8*)(Htb + (size_t)(dq0 + nt * 16 + c) * NN + j0 + q * 8);
#pragma unroll
        for (int nt = 0; nt < 4; ++nt)
            o[nt] = __builtin_amdgcn_mfma_f32_16x16x32_f16(af, bf[nt], o[nt], 0, 0, 0);
    }

    float* outb = out + (size_t)b * NN * DD;
#pragma unroll
    for (int r = 0; r < 4; ++r) {
        const int irow = q * 4 + r;
        const float rinv = 1.f / (sRedS[0][irow] + sRedS[1][irow] +
                                  sRedS[2][irow] + sRedS[3][irow]);
#pragma unroll
        for (int nt = 0; nt < 4; ++nt) {
            const int d = dq0 + nt * 16 + c;
            outb[(size_t)(i0 + irow) * DD + d] = o[nt][r] * rinv;
        }
    }
}

// ---------------- launcher ----------------
extern "C" void kernel_launch(void* const* d_in, const int* in_sizes, int n_in,
                              void* d_out, int out_size, void* d_ws, size_t ws_size,
                              hipStream_t stream) {
    const float* hidden = (const float*)d_in[0];
    const int*   adjp   = (const int*)d_in[1];
    const float* a0     = (const float*)d_in[2];
    const float* a1     = (const float*)d_in[3];
    const float* a2     = (const float*)d_in[4];
    const float* a3     = (const float*)d_in[5];
    float* outp = (float*)d_out;

    _Float16* h16  = (_Float16*)d_ws;
    _Float16* h16t = h16 + (size_t)BB * NN * DD;

    dim3 g1(DD / 32, NN / 32, BB);
    cvt_kernel<<<g1, 256, 0, stream>>>(hidden, h16, h16t);

    gat_kernel<<<BB * (NN / 16), 256, 0, stream>>>(h16, h16t, adjp, a0, a1, a2, a3, outp);
}

// Round 4
// 143.712 us; speedup vs baseline: 1.8722x; 1.2623x over previous
//
#include <hip/hip_runtime.h>
#include <hip/hip_fp16.h>

#define BB 32
#define NN 512
#define DD 256
#define NEG_INF -9e15f

typedef _Float16 half8 __attribute__((ext_vector_type(8)));
typedef _Float16 half4 __attribute__((ext_vector_type(4)));
typedef float v4f __attribute__((ext_vector_type(4)));
typedef float f4v __attribute__((ext_vector_type(4)));

// Fragment-swizzled layouts (16x16x32 MFMA, lane = q*16+c reads 16B at laneID*16B):
//  h16f : element h[b][n][d] at ((b*32 + n/16)*8 + d/32)*512 + ((d%32)/8)*128 + (n%16)*8 + d%8
//  h16tf: element h[b][j][d] at ((b*16 + d/16)*16 + j/32)*512 + ((j%32)/8)*128 + (d%16)*8 + j%8

// ---------------- pre-kernel: fp32 -> fp16 convert into swizzled layouts ----------------
__global__ __launch_bounds__(256) void cvt_kernel(const float* __restrict__ h,
                                                  _Float16* __restrict__ h16f,
                                                  _Float16* __restrict__ h16tf) {
    __shared__ _Float16 tile[32][36];
    const int d0 = blockIdx.x * 32;
    const int n0 = blockIdx.y * 32;
    const int b  = blockIdx.z;
    const int t  = threadIdx.x;

    // read: thread covers 4 contiguous d of one n-row (coalesced float4)
    const int nl = t >> 3;          // 0..31
    const int dq = (t & 7) * 4;     // 0,4,...,28
    f4v v = *(const f4v*)(h + ((size_t)b * NN + (n0 + nl)) * DD + d0 + dq);
    half4 hv = { (_Float16)v.x, (_Float16)v.y, (_Float16)v.z, (_Float16)v.w };

    // h16f write: nt=(n0+nl)/16, kc=d0/32, q=dq/8, c=(n0+nl)%16, e=dq%8
    {
        const size_t off = ((size_t)(b * 32 + ((n0 + nl) >> 4)) * 8 + (d0 >> 5)) * 512
                         + (dq >> 3) * 128 + ((n0 + nl) & 15) * 8 + (dq & 7);
        *(half4*)(h16f + off) = hv;
    }
    *(half4*)(&tile[nl][dq]) = hv;
    __syncthreads();

    // h16tf write: thread covers 4 contiguous j(=n) of one d-row
    const int dl = t >> 3;          // 0..31
    const int nq = (t & 7) * 4;     // 0,4,...,28
    half4 o = { tile[nq][dl], tile[nq + 1][dl], tile[nq + 2][dl], tile[nq + 3][dl] };
    {
        const size_t off = ((size_t)(b * 16 + ((d0 + dl) >> 4)) * 16 + (n0 >> 5)) * 512
                         + (nq >> 3) * 128 + ((d0 + dl) & 15) * 8 + (nq & 7);
        *(half4*)(h16tf + off) = o;
    }
}

// ---------------- fused GAT kernel ----------------
// Grid: BB*(NN/16) = 1024 blocks of 256 threads. Block = (b, 16-row i-block).
// Phase 1/2: wave w handles j-quarter [w*128, w*128+128) in 4 chunks of 32 j.
// Phase 3:   wave w handles d-quarter [w*64, w*64+64).
__global__ __launch_bounds__(256, 4) void gat_kernel(
    const _Float16* __restrict__ h16f,   // swizzled [B][N/16][D/32][4][16][8]
    const _Float16* __restrict__ h16tf,  // swizzled [B][D/16][N/32][4][16][8]
    const int* __restrict__ adj,         // [B][N][N]
    const float* __restrict__ a0, const float* __restrict__ a1,
    const float* __restrict__ a2, const float* __restrict__ a3,
    float* __restrict__ out)             // [B][N][D]
{
    __shared__ _Float16 sA[4][DD];            // 2 KB
    __shared__ _Float16 sAlpha[16][NN + 8];   // 16.6 KB
    __shared__ float sRedM[4][16];
    __shared__ float sRedS[4][16];

    const int tid  = threadIdx.x;
    const int wave = tid >> 6;
    const int lane = tid & 63;
    const int c    = lane & 15;   // MFMA: A.m / B.n / C.col
    const int q    = lane >> 4;   // MFMA: k-quad; C.row = q*4+reg
    const int foff = q * 128 + c * 8;   // lane's offset within a 512-elem fragment block

    const int blk  = blockIdx.x;
    const int b    = blk >> 5;    // 32 i-blocks per batch
    const int iblk = blk & 31;
    const int i0   = iblk * 16;

    sA[0][tid] = (_Float16)a0[tid];
    sA[1][tid] = (_Float16)a1[tid];
    sA[2][tid] = (_Float16)a2[tid];
    sA[3][tid] = (_Float16)a3[tid];
    __syncthreads();

    const _Float16* Hf   = h16f  + (size_t)b * NN * DD;   // 32 ntiles * 8 kc * 512
    const _Float16* Htf  = h16tf + (size_t)b * NN * DD;   // 16 dtiles * 16 jc * 512
    const int*      adjb = adj   + (size_t)b * NN * NN;
    const _Float16* hbase = Hf + (size_t)iblk * 8 * 512 + foff;   // A-side fragments, kc=s

    const int jbase = wave * 128;
    v4f S[8];   // selected scores: 16 rows x 128 j per wave

    // ---------------- phase 1: scores + select + leaky, 4 chunks of 32 j ----------------
#pragma unroll
    for (int g = 0; g < 4; ++g) {
        const int jg0 = jbase + g * 32;
        const _Float16* bbase = Hf + (size_t)(jg0 >> 4) * 8 * 512 + foff;
        v4f e[4][2];
#pragma unroll
        for (int k = 0; k < 4; ++k)
#pragma unroll
            for (int jt = 0; jt < 2; ++jt)
                e[k][jt] = (v4f){0.f, 0.f, 0.f, 0.f};

#pragma unroll
        for (int s = 0; s < 8; ++s) {
            half8 hf = *(const half8*)(hbase + s * 512);            // coalesced 1KB/wave
            half8 bfrag[2];
#pragma unroll
            for (int jt = 0; jt < 2; ++jt)
                bfrag[jt] = *(const half8*)(bbase + (jt * 8 + s) * 512);
#pragma unroll
            for (int k = 0; k < 4; ++k) {
                half8 aw = *(const half8*)(&sA[k][s * 32 + q * 8]); // LDS broadcast
                half8 af = hf * aw;                                  // (h_i * a_k)
#pragma unroll
                for (int jt = 0; jt < 2; ++jt)
                    e[k][jt] = __builtin_amdgcn_mfma_f32_16x16x32_f16(af, bfrag[jt], e[k][jt], 0, 0, 0);
            }
        }
#pragma unroll
        for (int jt = 0; jt < 2; ++jt) {
            const int j = jg0 + jt * 16 + c;
#pragma unroll
            for (int r = 0; r < 4; ++r) {
                const int i = i0 + q * 4 + r;
                const int v = adjb[(size_t)i * NN + j];
                float sc = (v == 1) ? e[0][jt][r]
                         : (v == 2) ? e[1][jt][r]
                         : (v == 3) ? e[2][jt][r]
                         : (v == 4) ? e[3][jt][r] : NEG_INF;
                sc = sc > 0.f ? sc : 0.2f * sc;
                S[g * 2 + jt][r] = sc;
            }
        }
    }

    // ---------------- phase 2: softmax over j (4-wave combine) ----------------
    float m4[4];
#pragma unroll
    for (int r = 0; r < 4; ++r) {
        float m = S[0][r];
#pragma unroll
        for (int t = 1; t < 8; ++t) m = fmaxf(m, S[t][r]);
#pragma unroll
        for (int off = 1; off < 16; off <<= 1)
            m = fmaxf(m, __shfl_xor(m, off, 64));
        m4[r] = m;
    }
    if (c == 0) {
#pragma unroll
        for (int r = 0; r < 4; ++r) sRedM[wave][q * 4 + r] = m4[r];
    }
    __syncthreads();

    float mf[4], sum4[4];
#pragma unroll
    for (int r = 0; r < 4; ++r) {
        float m = sRedM[0][q * 4 + r];
        m = fmaxf(m, sRedM[1][q * 4 + r]);
        m = fmaxf(m, sRedM[2][q * 4 + r]);
        m = fmaxf(m, sRedM[3][q * 4 + r]);
        mf[r]   = m;
        sum4[r] = 0.f;
    }
#pragma unroll
    for (int t = 0; t < 8; ++t) {
        const int j = jbase + t * 16 + c;
#pragma unroll
        for (int r = 0; r < 4; ++r) {
            float p = __expf(S[t][r] - mf[r]);   // NEG_INF path underflows to 0
            sum4[r] += p;
            sAlpha[q * 4 + r][j] = (_Float16)p;
        }
    }
#pragma unroll
    for (int r = 0; r < 4; ++r) {
#pragma unroll
        for (int off = 1; off < 16; off <<= 1)
            sum4[r] += __shfl_xor(sum4[r], off, 64);
    }
    if (c == 0) {
#pragma unroll
        for (int r = 0; r < 4; ++r) sRedS[wave][q * 4 + r] = sum4[r];
    }
    __syncthreads();

    // ---------------- phase 3: out = alpha @ H, wave = 64-d quarter ----------------
    const int dq0 = wave * 64;
    v4f o[4];
#pragma unroll
    for (int nt = 0; nt < 4; ++nt) o[nt] = (v4f){0.f, 0.f, 0.f, 0.f};

#pragma unroll
    for (int ks = 0; ks < 16; ++ks) {
        const int j0 = ks * 32;
        half8 af = *(const half8*)(&sAlpha[c][j0 + q * 8]);
        half8 bf[4];
#pragma unroll
        for (int nt = 0; nt < 4; ++nt)
            bf[nt] = *(const half8*)(Htf + (size_t)((wave * 4 + nt) * 16 + ks) * 512 + foff);
#pragma unroll
        for (int nt = 0; nt < 4; ++nt)
            o[nt] = __builtin_amdgcn_mfma_f32_16x16x32_f16(af, bf[nt], o[nt], 0, 0, 0);
    }

    float* outb = out + (size_t)b * NN * DD;
#pragma unroll
    for (int r = 0; r < 4; ++r) {
        const int irow = q * 4 + r;
        const float rinv = 1.f / (sRedS[0][irow] + sRedS[1][irow] +
                                  sRedS[2][irow] + sRedS[3][irow]);
#pragma unroll
        for (int nt = 0; nt < 4; ++nt) {
            const int d = dq0 + nt * 16 + c;
            outb[(size_t)(i0 + irow) * DD + d] = o[nt][r] * rinv;
        }
    }
}

// ---------------- launcher ----------------
extern "C" void kernel_launch(void* const* d_in, const int* in_sizes, int n_in,
                              void* d_out, int out_size, void* d_ws, size_t ws_size,
                              hipStream_t stream) {
    const float* hidden = (const float*)d_in[0];
    const int*   adjp   = (const int*)d_in[1];
    const float* a0     = (const float*)d_in[2];
    const float* a1     = (const float*)d_in[3];
    const float* a2     = (const float*)d_in[4];
    const float* a3     = (const float*)d_in[5];
    float* outp = (float*)d_out;

    _Float16* h16f  = (_Float16*)d_ws;
    _Float16* h16tf = h16f + (size_t)BB * NN * DD;

    dim3 g1(DD / 32, NN / 32, BB);
    cvt_kernel<<<g1, 256, 0, stream>>>(hidden, h16f, h16tf);

    gat_kernel<<<BB * (NN / 16), 256, 0, stream>>>(h16f, h16tf, adjp, a0, a1, a2, a3, outp);
}

// Round 5
// 131.342 us; speedup vs baseline: 2.0485x; 1.0942x over previous
//
#include <hip/hip_runtime.h>
#include <hip/hip_fp16.h>

#define BB 32
#define NN 512
#define DD 256
#define NEG_INF -9e15f

typedef _Float16 half8 __attribute__((ext_vector_type(8)));
typedef _Float16 half4 __attribute__((ext_vector_type(4)));
typedef float v4f __attribute__((ext_vector_type(4)));
typedef float f4v __attribute__((ext_vector_type(4)));

// Fragment-swizzled layouts (16x16x32 MFMA, lane = q*16+c reads 16B at laneID*16B):
//  h16f : element h[b][n][d] at ((b*32 + n/16)*8 + d/32)*512 + ((d%32)/8)*128 + (n%16)*8 + d%8
//  h16tf: element h[b][j][d] at ((b*16 + d/16)*16 + j/32)*512 + ((j%32)/8)*128 + (d%16)*8 + j%8

// ---------------- pre-kernel: fp32 -> fp16 convert into swizzled layouts ----------------
__global__ __launch_bounds__(256) void cvt_kernel(const float* __restrict__ h,
                                                  _Float16* __restrict__ h16f,
                                                  _Float16* __restrict__ h16tf) {
    __shared__ _Float16 tile[32][36];
    const int d0 = blockIdx.x * 32;
    const int n0 = blockIdx.y * 32;
    const int b  = blockIdx.z;
    const int t  = threadIdx.x;

    const int nl = t >> 3;          // 0..31
    const int dq = (t & 7) * 4;     // 0,4,...,28
    f4v v = *(const f4v*)(h + ((size_t)b * NN + (n0 + nl)) * DD + d0 + dq);
    half4 hv = { (_Float16)v.x, (_Float16)v.y, (_Float16)v.z, (_Float16)v.w };

    {
        const size_t off = ((size_t)(b * 32 + ((n0 + nl) >> 4)) * 8 + (d0 >> 5)) * 512
                         + (dq >> 3) * 128 + ((n0 + nl) & 15) * 8 + (dq & 7);
        *(half4*)(h16f + off) = hv;
    }
    *(half4*)(&tile[nl][dq]) = hv;
    __syncthreads();

    const int dl = t >> 3;          // 0..31
    const int nq = (t & 7) * 4;     // 0,4,...,28
    half4 o = { tile[nq][dl], tile[nq + 1][dl], tile[nq + 2][dl], tile[nq + 3][dl] };
    {
        const size_t off = ((size_t)(b * 16 + ((d0 + dl) >> 4)) * 16 + (n0 >> 5)) * 512
                         + (nq >> 3) * 128 + ((d0 + dl) & 15) * 8 + (nq & 7);
        *(half4*)(h16tf + off) = o;
    }
}

// ---------------- fused GAT kernel ----------------
// Grid: BB*(NN/16) = 1024 blocks of 256 threads. Block = (b, 16-row i-block).
// XCD swizzle: XCD x (= blk&7 under round-robin dispatch) owns batches 4x..4x+3,
// so each XCD's L2 holds its 4 batches' fragments (2.1 MB < 4 MiB).
__global__ __launch_bounds__(256, 4) void gat_kernel(
    const _Float16* __restrict__ h16f,   // swizzled [B][N/16][D/32][4][16][8]
    const _Float16* __restrict__ h16tf,  // swizzled [B][D/16][N/32][4][16][8]
    const int* __restrict__ adj,         // [B][N][N]
    const float* __restrict__ a0, const float* __restrict__ a1,
    const float* __restrict__ a2, const float* __restrict__ a3,
    float* __restrict__ out)             // [B][N][D]
{
    __shared__ _Float16 sA[4][DD];            // 2 KB
    __shared__ _Float16 sAlpha[16][NN + 8];   // 16.6 KB
    __shared__ float sRedM[4][16];
    __shared__ float sRedS[4][16];

    const int tid  = threadIdx.x;
    const int wave = tid >> 6;
    const int lane = tid & 63;
    const int c    = lane & 15;   // MFMA: A.m / B.n / C.col
    const int q    = lane >> 4;   // MFMA: k-quad; C.row = q*4+reg
    const int foff = q * 128 + c * 8;   // lane's offset within a 512-elem fragment block

    const int blk  = blockIdx.x;
    // XCD-aware decode: x = blk&7 (XCD), s = (blk>>3)&3, iblk = blk>>5
    const int b    = (blk & 7) * 4 + ((blk >> 3) & 3);
    const int iblk = blk >> 5;
    const int i0   = iblk * 16;

    sA[0][tid] = (_Float16)a0[tid];
    sA[1][tid] = (_Float16)a1[tid];
    sA[2][tid] = (_Float16)a2[tid];
    sA[3][tid] = (_Float16)a3[tid];
    __syncthreads();

    const _Float16* Hf   = h16f  + (size_t)b * NN * DD;   // 32 ntiles * 8 kc * 512
    const _Float16* Htf  = h16tf + (size_t)b * NN * DD;   // 16 dtiles * 16 jc * 512
    const int*      adjb = adj   + (size_t)b * NN * NN;
    const _Float16* hbase = Hf + (size_t)iblk * 8 * 512 + foff;   // A-side fragments

    const int jbase = wave * 128;
    v4f S[8];   // selected scores: 16 rows x 128 j per wave

    // ---------------- phase 1: scores + select + leaky, 4 chunks of 32 j ----------------
#pragma unroll
    for (int g = 0; g < 4; ++g) {
        const int jg0 = jbase + g * 32;
        const _Float16* bbase = Hf + (size_t)(jg0 >> 4) * 8 * 512 + foff;

        // prefetch adj for this chunk BEFORE the MFMA loop (hides 200-900 cyc)
        int av[2][4];
#pragma unroll
        for (int jt = 0; jt < 2; ++jt)
#pragma unroll
            for (int r = 0; r < 4; ++r)
                av[jt][r] = adjb[(size_t)(i0 + q * 4 + r) * NN + (jg0 + jt * 16 + c)];

        v4f e[4][2];
#pragma unroll
        for (int k = 0; k < 4; ++k)
#pragma unroll
            for (int jt = 0; jt < 2; ++jt)
                e[k][jt] = (v4f){0.f, 0.f, 0.f, 0.f};

#pragma unroll
        for (int s = 0; s < 8; ++s) {
            half8 hf = *(const half8*)(hbase + s * 512);            // L1-hot across g
            half8 bfrag[2];
#pragma unroll
            for (int jt = 0; jt < 2; ++jt)
                bfrag[jt] = *(const half8*)(bbase + (jt * 8 + s) * 512);
#pragma unroll
            for (int k = 0; k < 4; ++k) {
                half8 aw = *(const half8*)(&sA[k][s * 32 + q * 8]); // LDS broadcast
                half8 af = hf * aw;                                  // (h_i * a_k)
#pragma unroll
                for (int jt = 0; jt < 2; ++jt)
                    e[k][jt] = __builtin_amdgcn_mfma_f32_16x16x32_f16(af, bfrag[jt], e[k][jt], 0, 0, 0);
            }
        }
#pragma unroll
        for (int jt = 0; jt < 2; ++jt) {
#pragma unroll
            for (int r = 0; r < 4; ++r) {
                const int v = av[jt][r];
                float sc = (v == 1) ? e[0][jt][r]
                         : (v == 2) ? e[1][jt][r]
                         : (v == 3) ? e[2][jt][r]
                         : (v == 4) ? e[3][jt][r] : NEG_INF;
                sc = sc > 0.f ? sc : 0.2f * sc;
                S[g * 2 + jt][r] = sc;
            }
        }
    }

    // ---------------- phase 2: softmax over j (4-wave combine) ----------------
    float m4[4];
#pragma unroll
    for (int r = 0; r < 4; ++r) {
        float m = S[0][r];
#pragma unroll
        for (int t = 1; t < 8; ++t) m = fmaxf(m, S[t][r]);
#pragma unroll
        for (int off = 1; off < 16; off <<= 1)
            m = fmaxf(m, __shfl_xor(m, off, 64));
        m4[r] = m;
    }
    if (c == 0) {
#pragma unroll
        for (int r = 0; r < 4; ++r) sRedM[wave][q * 4 + r] = m4[r];
    }
    __syncthreads();

    float mf[4], sum4[4];
#pragma unroll
    for (int r = 0; r < 4; ++r) {
        float m = sRedM[0][q * 4 + r];
        m = fmaxf(m, sRedM[1][q * 4 + r]);
        m = fmaxf(m, sRedM[2][q * 4 + r]);
        m = fmaxf(m, sRedM[3][q * 4 + r]);
        mf[r]   = m;
        sum4[r] = 0.f;
    }
#pragma unroll
    for (int t = 0; t < 8; ++t) {
        const int j = jbase + t * 16 + c;
#pragma unroll
        for (int r = 0; r < 4; ++r) {
            float p = __expf(S[t][r] - mf[r]);   // NEG_INF path underflows to 0
            sum4[r] += p;
            sAlpha[q * 4 + r][j] = (_Float16)p;
        }
    }
#pragma unroll
    for (int r = 0; r < 4; ++r) {
#pragma unroll
        for (int off = 1; off < 16; off <<= 1)
            sum4[r] += __shfl_xor(sum4[r], off, 64);
    }
    if (c == 0) {
#pragma unroll
        for (int r = 0; r < 4; ++r) sRedS[wave][q * 4 + r] = sum4[r];
    }
    __syncthreads();

    // ---------------- phase 3: out = alpha @ H, wave = 64-d quarter ----------------
    const int dq0 = wave * 64;
    v4f o[4];
#pragma unroll
    for (int nt = 0; nt < 4; ++nt) o[nt] = (v4f){0.f, 0.f, 0.f, 0.f};

#pragma unroll
    for (int ks = 0; ks < 16; ++ks) {
        const int j0 = ks * 32;
        half8 af = *(const half8*)(&sAlpha[c][j0 + q * 8]);
        half8 bf[4];
#pragma unroll
        for (int nt = 0; nt < 4; ++nt)
            bf[nt] = *(const half8*)(Htf + (size_t)((wave * 4 + nt) * 16 + ks) * 512 + foff);
#pragma unroll
        for (int nt = 0; nt < 4; ++nt)
            o[nt] = __builtin_amdgcn_mfma_f32_16x16x32_f16(af, bf[nt], o[nt], 0, 0, 0);
    }

    float* outb = out + (size_t)b * NN * DD;
#pragma unroll
    for (int r = 0; r < 4; ++r) {
        const int irow = q * 4 + r;
        const float rinv = 1.f / (sRedS[0][irow] + sRedS[1][irow] +
                                  sRedS[2][irow] + sRedS[3][irow]);
#pragma unroll
        for (int nt = 0; nt < 4; ++nt) {
            const int d = dq0 + nt * 16 + c;
            outb[(size_t)(i0 + irow) * DD + d] = o[nt][r] * rinv;
        }
    }
}

// ---------------- launcher ----------------
extern "C" void kernel_launch(void* const* d_in, const int* in_sizes, int n_in,
                              void* d_out, int out_size, void* d_ws, size_t ws_size,
                              hipStream_t stream) {
    const float* hidden = (const float*)d_in[0];
    const int*   adjp   = (const int*)d_in[1];
    const float* a0     = (const float*)d_in[2];
    const float* a1     = (const float*)d_in[3];
    const float* a2     = (const float*)d_in[4];
    const float* a3     = (const float*)d_in[5];
    float* outp = (float*)d_out;

    _Float16* h16f  = (_Float16*)d_ws;
    _Float16* h16tf = h16f + (size_t)BB * NN * DD;

    dim3 g1(DD / 32, NN / 32, BB);
    cvt_kernel<<<g1, 256, 0, stream>>>(hidden, h16f, h16tf);

    gat_kernel<<<BB * (NN / 16), 256, 0, stream>>>(h16f, h16tf, adjp, a0, a1, a2, a3, outp);
}